// Round 1
// baseline (165.429 us; speedup 1.0000x reference)
//
#include <hip/hip_runtime.h>

// Problem constants (from setup_inputs: nb=16, k=11, ps=10, with_padding=1, rgb 1x3x2048x2048 f32)
constexpr int H   = 2048;
constexpr int W   = 2048;
constexpr int NB  = 16;             // param_num_bins
constexpr int K   = 11;             // param_kernel_size
constexpr int PS  = 10;             // param_pixel_size
constexpr int PAD = (K - 1) / 2;    // 5
constexpr int HO  = (H + 2 * PAD - K) / PS + 1;  // 205
constexpr int WO  = (W + 2 * PAD - K) / PS + 1;  // 205
constexpr int OH  = HO * (PS + 1);  // 2255 (with_padding == 1)
constexpr int OW  = WO * (PS + 1);  // 2255

// Kernel 1: 4 threads per window. Each thread handles rows {sub, sub+4, sub+8}
// of the 11x11 window. Histogram packed in 2x u64 (16 fields x 8 bits; max
// count 121 so no overflow). Pass 2 sums rgb only for the argmax bin.
__global__ __launch_bounds__(256) void window_kernel(const float* __restrict__ rgb,
                                                     float* __restrict__ val) {
    int t   = blockIdx.x * blockDim.x + threadIdx.x;
    int win = t >> 2;
    int sub = t & 3;
    if (win >= HO * WO) return;
    int wy = win / WO;
    int wx = win - wy * WO;
    int y0 = wy * PS - PAD;
    int x0 = wx * PS - PAD;

    const float* __restrict__ rp = rgb;
    const float* __restrict__ gp = rgb + H * W;
    const float* __restrict__ bp = rgb + 2 * H * W;

    // ---- pass 1: packed histogram ----
    unsigned long long lo = 0ull, hi = 0ull;
    for (int j = sub; j < K; j += 4) {
        int y = y0 + j;
        if ((unsigned)y >= (unsigned)H) continue;
        long roff = (long)y * W;
        #pragma unroll
        for (int i = 0; i < K; ++i) {
            int x = x0 + i;
            if ((unsigned)x >= (unsigned)W) continue;
            float r = rp[roff + x];
            float g = gp[roff + x];
            float b = bp[roff + x];
            float mean = (r + g + b) / 3.0f;          // matches jnp.mean in fp32
            int idx = (int)(mean * 0.0625f);          // exact: (mean/256)*16 (pow2 steps)
            unsigned long long inc = 1ull << ((idx & 7) * 8);
            if (idx < 8) lo += inc; else hi += inc;
        }
    }
    // combine the 4 lanes of this window (byte fields: total <= 121, no overflow)
    lo += __shfl_xor(lo, 1, 4);
    lo += __shfl_xor(lo, 2, 4);
    hi += __shfl_xor(hi, 1, 4);
    hi += __shfl_xor(hi, 2, 4);

    // ---- argmax over 16 bins, first-tie-wins (jnp.argmax semantics) ----
    int best  = 0;
    int bestc = (int)(lo & 0xffull);
    #pragma unroll
    for (int b = 1; b < NB; ++b) {
        unsigned long long wsel = (b < 8) ? lo : hi;
        int c = (int)((wsel >> ((b & 7) * 8)) & 0xffull);
        if (c > bestc) { bestc = c; best = b; }
    }

    // ---- pass 2: sum rgb where idx == best (loads are L1-hot) ----
    float sr = 0.f, sg = 0.f, sb = 0.f;
    for (int j = sub; j < K; j += 4) {
        int y = y0 + j;
        if ((unsigned)y >= (unsigned)H) continue;
        long roff = (long)y * W;
        #pragma unroll
        for (int i = 0; i < K; ++i) {
            int x = x0 + i;
            if ((unsigned)x >= (unsigned)W) continue;
            float r = rp[roff + x];
            float g = gp[roff + x];
            float b = bp[roff + x];
            float mean = (r + g + b) / 3.0f;
            int idx = (int)(mean * 0.0625f);
            if (idx == best) { sr += r; sg += g; sb += b; }
        }
    }
    sr += __shfl_xor(sr, 1, 4);
    sr += __shfl_xor(sr, 2, 4);
    sg += __shfl_xor(sg, 1, 4);
    sg += __shfl_xor(sg, 2, 4);
    sb += __shfl_xor(sb, 1, 4);
    sb += __shfl_xor(sb, 2, 4);

    if (sub == 0) {
        float cm = (float)bestc;      // cmax > 0 always (window has >= 36 px)
        int o = wy * WO + wx;
        val[o]               = sr / cm;
        val[HO * WO + o]     = sg / cm;
        val[2 * HO * WO + o] = sb / cm;
    }
}

// Kernel 2: one thread per output element, coalesced writes. Each 11x11 output
// block = 10x10 replicated window value + zero row/col (with_padding == 1).
__global__ __launch_bounds__(256) void write_kernel(const float* __restrict__ val,
                                                    float* __restrict__ out) {
    long t = (long)blockIdx.x * blockDim.x + threadIdx.x;
    if (t >= 3L * OH * OW) return;
    int c   = (int)(t / (long)(OH * OW));
    int rem = (int)(t - (long)c * (OH * OW));
    int y   = rem / OW;
    int x   = rem - y * OW;
    int by = y / (PS + 1), iy = y - by * (PS + 1);
    int bx = x / (PS + 1), ix = x - bx * (PS + 1);
    float v = 0.0f;
    if (iy != PS && ix != PS) v = val[c * HO * WO + by * WO + bx];
    out[t] = v;
}

extern "C" void kernel_launch(void* const* d_in, const int* in_sizes, int n_in,
                              void* d_out, int out_size, void* d_ws, size_t ws_size,
                              hipStream_t stream) {
    const float* rgb = (const float*)d_in[0];
    float* val = (float*)d_ws;           // 3*205*205 floats = 504,300 B scratch
    float* out = (float*)d_out;

    int nthreads1 = HO * WO * 4;         // 4 threads per window
    window_kernel<<<(nthreads1 + 255) / 256, 256, 0, stream>>>(rgb, val);

    long total = 3L * OH * OW;           // 15,255,075 output elements
    write_kernel<<<(int)((total + 255) / 256), 256, 0, stream>>>(val, out);
}

// Round 2
// 131.587 us; speedup vs baseline: 1.2572x; 1.2572x over previous
//
#include <hip/hip_runtime.h>

// Problem constants (nb=16, k=11, ps=10, with_padding=1, rgb 1x3x2048x2048 f32)
constexpr int H   = 2048;
constexpr int W   = 2048;
constexpr int NB  = 16;
constexpr int K   = 11;
constexpr int PS  = 10;
constexpr int PAD = (K - 1) / 2;                 // 5
constexpr int HO  = (H + 2 * PAD - K) / PS + 1;  // 205
constexpr int WO  = (W + 2 * PAD - K) / PS + 1;  // 205
constexpr int OH  = HO * (PS + 1);               // 2255
constexpr int OW  = WO * (PS + 1);               // 2255
constexpr int NTOT = 3 * OH * OW;                // 15,255,075

constexpr int TW  = 4;                 // 4x4 windows per block
constexpr int R   = TW * PS + K - 1;   // 41x41 pixel region per tile
constexpr int NPX = R * R;             // 1681

// Kernel 1: one block = 4x4 window tile. Stage 41x41 rgb region into LDS with
// coalesced loads (each pixel fetched from HBM exactly once). 16 threads per
// window; each caches ~8 pixels (rgb + bin idx) in registers. Pass 1: packed
// u64 histogram + shfl_xor reduce (width 16) + first-tie-wins argmax.
// Pass 2: register-only conditional sums.
__global__ __launch_bounds__(256) void window_kernel(const float* __restrict__ rgb,
                                                     float* __restrict__ val) {
    __shared__ float ls_r[NPX];
    __shared__ float ls_g[NPX];
    __shared__ float ls_b[NPX];

    int tid = threadIdx.x;
    int wy0 = blockIdx.y * TW;
    int wx0 = blockIdx.x * TW;
    int gy0 = wy0 * PS - PAD;
    int gx0 = wx0 * PS - PAD;

    const float* __restrict__ rp = rgb;
    const float* __restrict__ gp = rgb + H * W;
    const float* __restrict__ bp = rgb + 2 * H * W;

    // ---- stage tile into LDS (coalesced) ----
    for (int p = tid; p < NPX; p += 256) {
        int j = p / R, i = p - j * R;
        int y = gy0 + j, x = gx0 + i;
        float r, g, b;
        if ((unsigned)y < (unsigned)H && (unsigned)x < (unsigned)W) {
            long o = (long)y * W + x;
            r = rp[o]; g = gp[o]; b = bp[o];
        } else {
            r = g = b = 1.0e9f;   // sentinel: idx saturates out of [0,16)
        }
        ls_r[p] = r; ls_g[p] = g; ls_b[p] = b;
    }
    __syncthreads();

    int wid = tid >> 4;             // 0..15  local window
    int sub = tid & 15;             // 0..15  lane within window
    int wly = wid >> 2, wlx = wid & 3;
    int wy = wy0 + wly, wx = wx0 + wlx;
    bool valid = (wy < HO) && (wx < WO);
    int base = (wly * PS) * R + (wlx * PS);

    // ---- pass 1: load my pixels, cache in regs, build packed histogram ----
    float cr[8], cg[8], cb[8];
    int   ci[8];
    unsigned long long lo = 0ull, hi = 0ull;
    #pragma unroll
    for (int t = 0; t < 8; ++t) {
        int p = sub + 16 * t;       // t<7 always <121; t==7 valid iff sub<9
        float r = 0.f, g = 0.f, b = 0.f;
        int idx = 9999;
        if (p < K * K) {
            int j = p / K, i = p - j * K;
            int addr = base + j * R + i;
            r = ls_r[addr]; g = ls_g[addr]; b = ls_b[addr];
            float mean = (r + g + b) / 3.0f;      // matches np.mean fp32 semantics
            idx = (int)(mean * 0.0625f);          // exact pow2 scaling of mean/256*16
        }
        cr[t] = r; cg[t] = g; cb[t] = b; ci[t] = idx;
        if ((unsigned)idx < 8u)       lo += 1ull << (idx * 8);
        else if ((unsigned)idx < 16u) hi += 1ull << ((idx - 8) * 8);
    }
    // reduce histogram across the 16 lanes of this window (byte fields, max 121)
    #pragma unroll
    for (int s = 1; s < 16; s <<= 1) {
        lo += __shfl_xor(lo, s, 16);
        hi += __shfl_xor(hi, s, 16);
    }

    // ---- argmax over 16 bins, first-tie-wins (jnp.argmax) ----
    int best = 0;
    int bestc = (int)(lo & 0xffull);
    #pragma unroll
    for (int b = 1; b < NB; ++b) {
        unsigned long long wsel = (b < 8) ? lo : hi;
        int c = (int)((wsel >> ((b & 7) * 8)) & 0xffull);
        if (c > bestc) { bestc = c; best = b; }
    }

    // ---- pass 2: register-only conditional sums ----
    float sr = 0.f, sg = 0.f, sb = 0.f;
    #pragma unroll
    for (int t = 0; t < 8; ++t) {
        if (ci[t] == best) { sr += cr[t]; sg += cg[t]; sb += cb[t]; }
    }
    #pragma unroll
    for (int s = 1; s < 16; s <<= 1) {
        sr += __shfl_xor(sr, s, 16);
        sg += __shfl_xor(sg, s, 16);
        sb += __shfl_xor(sb, s, 16);
    }

    if (sub == 0 && valid) {
        float cm = (float)bestc;     // >0 always (window has >= 36 in-bounds px)
        int o = wy * WO + wx;
        val[o]               = sr / cm;
        val[HO * WO + o]     = sg / cm;
        val[2 * HO * WO + o] = sb / cm;
    }
}

// Kernel 2: 4 output elements per thread, float4 stores. Each 11x11 block of
// the output = 10x10 replicated window value + zero row/col.
__global__ __launch_bounds__(256) void write_kernel(const float* __restrict__ val,
                                                    float* __restrict__ out) {
    int t4 = (blockIdx.x * 256 + threadIdx.x) * 4;
    if (t4 >= NTOT) return;
    float vv[4];
    #pragma unroll
    for (int e = 0; e < 4; ++e) {
        int t = t4 + e;
        float v = 0.0f;
        if (t < NTOT) {
            int c   = t / (OH * OW);
            int rem = t - c * (OH * OW);
            int y   = rem / OW;
            int x   = rem - y * OW;
            int by = y / (PS + 1), iy = y - by * (PS + 1);
            int bx = x / (PS + 1), ix = x - bx * (PS + 1);
            if (iy != PS && ix != PS) v = val[c * HO * WO + by * WO + bx];
        }
        vv[e] = v;
    }
    if (t4 + 3 < NTOT) {
        *(float4*)(out + t4) = make_float4(vv[0], vv[1], vv[2], vv[3]);
    } else {
        #pragma unroll
        for (int e = 0; e < 4; ++e)
            if (t4 + e < NTOT) out[t4 + e] = vv[e];
    }
}

extern "C" void kernel_launch(void* const* d_in, const int* in_sizes, int n_in,
                              void* d_out, int out_size, void* d_ws, size_t ws_size,
                              hipStream_t stream) {
    const float* rgb = (const float*)d_in[0];
    float* val = (float*)d_ws;            // 3*205*205 floats = 504,300 B scratch
    float* out = (float*)d_out;

    dim3 grid1((WO + TW - 1) / TW, (HO + TW - 1) / TW);   // 52 x 52
    window_kernel<<<grid1, 256, 0, stream>>>(rgb, val);

    int nblk2 = (NTOT + 4 * 256 - 1) / (4 * 256);         // 14898
    write_kernel<<<nblk2, 256, 0, stream>>>(val, out);
}